// Round 1
// baseline (198.106 us; speedup 1.0000x reference)
//
#include <hip/hip_runtime.h>
#include <math.h>

// QNN: 8 qubits, DIM=256, 2 strongly-entangling layers, B samples.
// Algebra:
//  - Embedding RX(x_q) fuses with layer-1 RX(w[0,q,0]) -> RX(x_q + w0).
//  - State after layer-1 rotations = product state  v_q = RZ(g)RY(b)RX(a)|0>.
//  - CNOT ring is a linear basis permutation g over GF(2):
//      c0=b0^b7, c1=b0^b1^b7, c2=b1^b2, c3=b2^b3, c4=b3^b4,
//      c5=b4^b5, c6=b5^b6, c7=b6^b7            (b_q = wire-q bit, wire0=MSB)
//    Ring-1 folded into product expansion (amp[j] = prod_q v_q[beta_q(j)]).
//    Ring-2 folded into measurement sign masks:
//      <Z_w> = sum_i p_i * (-1)^popc(m_w & i),
//      m = {0x7F,0xC0,0xE0,0xF0,0xF8,0xFC,0xFE,0xFF}.
//  - Only layer-2's 8 fused 1q gates G=RZ*RY*RX are applied as gates;
//    SU(2): G11=conj(G00), G10=-conj(G01) -> store 4 floats/qubit.
// Mapping: 1 wave = 1 sample. Lane L holds amps j=4L+r, r=0..3.
//   wire q (0..5) -> lane bit 5-q (shfl_xor mask 32>>q); wires 6,7 in-register.

// ---------------- setup: shared-weight trig -> d_ws (72 floats) --------------
// params[q*5 + {0..4}]       = {w0, cos(b/2), sin(b/2), cos(g/2), sin(g/2)}  (layer1)
// params[40 + q*4 + {0..3}]  = {G00r, G00i, G01r, G01i}                      (layer2)
__global__ void qnn_setup(const float* __restrict__ w, float* __restrict__ p) {
    int t = threadIdx.x;
    if (t < 8) {
        int q = t;
        const float* wq = w + q * 3;            // layer 0
        p[q*5+0] = wq[0];
        p[q*5+1] = cosf(wq[1] * 0.5f);
        p[q*5+2] = sinf(wq[1] * 0.5f);
        p[q*5+3] = cosf(wq[2] * 0.5f);
        p[q*5+4] = sinf(wq[2] * 0.5f);
    } else if (t < 16) {
        int q = t - 8;
        const float* wq = w + (8 + q) * 3;      // layer 1
        float ca = cosf(wq[0]*0.5f), sa = sinf(wq[0]*0.5f);
        float cb = cosf(wq[1]*0.5f), sb = sinf(wq[1]*0.5f);
        float cg = cosf(wq[2]*0.5f), sg = sinf(wq[2]*0.5f);
        float A = cb*ca, Bv = sb*sa, C = sb*ca, D = cb*sa;
        float* gp = p + 40 + q*4;
        gp[0] = cg*A + sg*Bv;       // G00r   (G00 = e^{-ig/2}(cb*ca + i sb*sa))
        gp[1] = cg*Bv - sg*A;       // G00i
        gp[2] = -(cg*C + sg*D);     // G01r   (G01 = -e^{-ig/2}(sb*ca + i cb*sa))
        gp[3] = sg*C - cg*D;        // G01i
    }
}

struct V2c { float r0, i0, r1, i1; };   // v[0], v[1] (complex)

__device__ __forceinline__ V2c make_v(float ang_half, float cb, float sb,
                                      float cg, float sg) {
    float sa, ca;
    __sincosf(ang_half, &sa, &ca);
    float A = cb*ca, Bv = sb*sa, C = sb*ca, D = cb*sa;
    V2c v;
    v.r0 = cg*A + sg*Bv;  v.i0 = cg*Bv - sg*A;    // e^{-ig/2}(A + iB)
    v.r1 = cg*C + sg*D;   v.i1 = sg*C - cg*D;     // e^{+ig/2}(C - iD)
    return v;
}

__global__ __launch_bounds__(256) void qnn_main(
        const float* __restrict__ x, const float* __restrict__ p,
        float* __restrict__ out, int B)
{
    const int lane = threadIdx.x & 63;
    const int b = blockIdx.x * 4 + (threadIdx.x >> 6);
    if (b >= B) return;                       // wave-uniform
    const int L = lane;
    const int L5=(L>>5)&1, L4=(L>>4)&1, L3=(L>>3)&1,
              L2=(L>>2)&1, L1=(L>>1)&1, L0=L&1;

    float xv = 0.f;
    if (lane < 8) xv = x[(size_t)b*8 + lane];

    // ---- per-qubit 2-vectors (embedding + layer-1 rotations fused) ----
    V2c V[8];
#pragma unroll
    for (int q = 0; q < 8; ++q) {
        float ang = __shfl(xv, q, 64) + p[q*5+0];
        V[q] = make_v(ang*0.5f, p[q*5+1], p[q*5+2], p[q*5+3], p[q*5+4]);
    }

    // ---- product expansion with ring-1 folded in ----
    // beta0=L5^r0  beta1=L5^L4^r0  beta2=L4^L3  beta3=L3^L2
    // beta4=L2^L1  beta5=L1^L0     beta6=L0^r1  beta7=r1^r0
    const int s0=L5, s1=L5^L4, s2=L4^L3, s3=L3^L2, s4=L2^L1, s5=L1^L0, s6=L0;

    float Pr = s2 ? V[2].r1 : V[2].r0;
    float Pi = s2 ? V[2].i1 : V[2].i0;
    {   float fr = s3 ? V[3].r1 : V[3].r0, fi = s3 ? V[3].i1 : V[3].i0;
        float nr = Pr*fr - Pi*fi, ni = Pr*fi + Pi*fr; Pr = nr; Pi = ni; }
    {   float fr = s4 ? V[4].r1 : V[4].r0, fi = s4 ? V[4].i1 : V[4].i0;
        float nr = Pr*fr - Pi*fi, ni = Pr*fi + Pi*fr; Pr = nr; Pi = ni; }
    {   float fr = s5 ? V[5].r1 : V[5].r0, fi = s5 ? V[5].i1 : V[5].i0;
        float nr = Pr*fr - Pi*fi, ni = Pr*fi + Pi*fr; Pr = nr; Pi = ni; }

    float e0r, e0i, e1r, e1i;                     // q0*q1 for r0=0 / r0=1
    {   float a0r = s0 ? V[0].r1 : V[0].r0, a0i = s0 ? V[0].i1 : V[0].i0;
        float b0r = s1 ? V[1].r1 : V[1].r0, b0i = s1 ? V[1].i1 : V[1].i0;
        e0r = a0r*b0r - a0i*b0i; e0i = a0r*b0i + a0i*b0r;
        float a1r = s0 ? V[0].r0 : V[0].r1, a1i = s0 ? V[0].i0 : V[0].i1;
        float b1r = s1 ? V[1].r0 : V[1].r1, b1i = s1 ? V[1].i0 : V[1].i1;
        e1r = a1r*b1r - a1i*b1i; e1i = a1r*b1i + a1i*b1r; }
    float M0r = Pr*e0r - Pi*e0i, M0i = Pr*e0i + Pi*e0r;
    float M1r = Pr*e1r - Pi*e1i, M1i = Pr*e1i + Pi*e1r;

    float w0r = s6 ? V[6].r1 : V[6].r0, w0i = s6 ? V[6].i1 : V[6].i0;  // r1=0
    float w1r = s6 ? V[6].r0 : V[6].r1, w1i = s6 ? V[6].i0 : V[6].i1;  // r1=1
    float u0r = w0r*V[7].r0 - w0i*V[7].i0, u0i = w0r*V[7].i0 + w0i*V[7].r0;
    float u1r = w0r*V[7].r1 - w0i*V[7].i1, u1i = w0r*V[7].i1 + w0i*V[7].r1;
    float u2r = w1r*V[7].r1 - w1i*V[7].i1, u2i = w1r*V[7].i1 + w1i*V[7].r1;
    float u3r = w1r*V[7].r0 - w1i*V[7].i0, u3i = w1r*V[7].i0 + w1i*V[7].r0;

    float ar[4], ai[4];
    ar[0] = M0r*u0r - M0i*u0i; ai[0] = M0r*u0i + M0i*u0r;
    ar[1] = M1r*u1r - M1i*u1i; ai[1] = M1r*u1i + M1i*u1r;
    ar[2] = M0r*u2r - M0i*u2i; ai[2] = M0r*u2i + M0i*u2r;
    ar[3] = M1r*u3r - M1i*u3i; ai[3] = M1r*u3i + M1i*u3r;

    // ---- layer-2 fused gates: wires 0..5 cross-lane ----
#pragma unroll
    for (int q = 0; q < 6; ++q) {
        const float g00r = p[40+q*4+0], g00i = p[40+q*4+1];
        const float g01r = p[40+q*4+2], g01i = p[40+q*4+3];
        const int t = (L >> (5-q)) & 1;
        // t=0: d=G00, o=G01 ; t=1: d=conj(G00), o=-conj(G01)
        const float di  = t ? -g00i : g00i;
        const float orr = t ? -g01r : g01r;
        const int mask = 32 >> q;
#pragma unroll
        for (int r = 0; r < 4; ++r) {
            float prr = __shfl_xor(ar[r], mask, 64);
            float pii = __shfl_xor(ai[r], mask, 64);
            float nr = g00r*ar[r] - di*ai[r] + orr*prr - g01i*pii;
            float ni = g00r*ai[r] + di*ar[r] + orr*pii + g01i*prr;
            ar[r] = nr; ai[r] = ni;
        }
    }
    // ---- wire 6 (bit1): pairs (0,2),(1,3) ----
    {
        const float g00r = p[40+24+0], g00i = p[40+24+1];
        const float g01r = p[40+24+2], g01i = p[40+24+3];
#pragma unroll
        for (int k = 0; k < 2; ++k) {
            int i0 = k, i1 = k + 2;
            float a0r=ar[i0], a0i=ai[i0], a1r=ar[i1], a1i=ai[i1];
            ar[i0] =  g00r*a0r - g00i*a0i + g01r*a1r - g01i*a1i;
            ai[i0] =  g00r*a0i + g00i*a0r + g01r*a1i + g01i*a1r;
            ar[i1] = -g01r*a0r - g01i*a0i + g00r*a1r + g00i*a1i;
            ai[i1] = -g01r*a0i + g01i*a0r + g00r*a1i - g00i*a1r;
        }
    }
    // ---- wire 7 (bit0): pairs (0,1),(2,3) ----
    {
        const float g00r = p[40+28+0], g00i = p[40+28+1];
        const float g01r = p[40+28+2], g01i = p[40+28+3];
#pragma unroll
        for (int k = 0; k < 2; ++k) {
            int i0 = 2*k, i1 = 2*k + 1;
            float a0r=ar[i0], a0i=ai[i0], a1r=ar[i1], a1i=ai[i1];
            ar[i0] =  g00r*a0r - g00i*a0i + g01r*a1r - g01i*a1i;
            ai[i0] =  g00r*a0i + g00i*a0r + g01r*a1i + g01i*a1r;
            ar[i1] = -g01r*a0r - g01i*a0i + g00r*a1r + g00i*a1i;
            ai[i1] = -g01r*a0i + g01i*a0r + g00r*a1i - g00i*a1r;
        }
    }

    // ---- probs + ring-2-folded signed reductions ----
    float p0 = ar[0]*ar[0] + ai[0]*ai[0];
    float p1 = ar[1]*ar[1] + ai[1]*ai[1];
    float p2 = ar[2]*ar[2] + ai[2]*ai[2];
    float p3 = ar[3]*ar[3] + ai[3]*ai[3];
    float S0 = (p0+p1) + (p2+p3);   // lo mask 0
    float S2 = (p0+p1) - (p2+p3);   // lo mask 2
    float S3 = (p0-p1) - (p2-p3);   // lo mask 3

    const int   hiM[8]  = {31, 48, 56, 60, 62, 63, 63, 63};
    const float base[8] = {S3, S0, S0, S0, S0, S0, S2, S3};
    float res[8];
#pragma unroll
    for (int w = 0; w < 8; ++w) {
        float v = base[w];
        if (__popc(hiM[w] & L) & 1) v = -v;
#pragma unroll
        for (int s = 1; s < 64; s <<= 1) v += __shfl_xor(v, s, 64);
        res[w] = v;
    }
    float o = res[0];
    o = (lane==1) ? res[1] : o;
    o = (lane==2) ? res[2] : o;
    o = (lane==3) ? res[3] : o;
    o = (lane==4) ? res[4] : o;
    o = (lane==5) ? res[5] : o;
    o = (lane==6) ? res[6] : o;
    o = (lane==7) ? res[7] : o;
    if (lane < 8) out[(size_t)b*8 + lane] = o;
}

extern "C" void kernel_launch(void* const* d_in, const int* in_sizes, int n_in,
                              void* d_out, int out_size, void* d_ws, size_t ws_size,
                              hipStream_t stream) {
    const float* x = (const float*)d_in[0];
    const float* w = (const float*)d_in[1];
    float* out     = (float*)d_out;
    float* params  = (float*)d_ws;          // 72 floats
    int B = in_sizes[0] / 8;

    qnn_setup<<<1, 64, 0, stream>>>(w, params);
    int blocks = (B + 3) / 4;               // 4 waves/block, 1 sample/wave
    qnn_main<<<blocks, 256, 0, stream>>>(x, params, out, B);
}

// Round 2
// 170.047 us; speedup vs baseline: 1.1650x; 1.1650x over previous
//
#include <hip/hip_runtime.h>
#include <math.h>

// QNN: 8 qubits, DIM=256, 2 entangling layers, B samples. See derivation:
//  - RX(x_q) fuses with layer-1 RX -> product state v_q = RZ RY RX |0>.
//  - CNOT ring 1 folded into product expansion (GF(2) basis permutation).
//  - CNOT ring 2 folded into measurement sign masks m_w.
//  - Layer-2 = 8 fused SU(2) gates (shared weights, precomputed in d_ws).
//  - <Z_w> = 8 coefficients of WHT_256(probs) = (in-lane 4-WHT) x (cross-lane 64-WHT).
// Mapping: 1 wave = 1 sample; lane L holds amps j=4L+r (r=0..3) as float2 (re,im).
// R2: packed-f32 (v_pk_fma_f32) complex math + shared-WHT reduction + ds_swizzle.

typedef float f2 __attribute__((ext_vector_type(2)));

__device__ __forceinline__ f2 iswap(f2 v) { return (f2){-v.y, v.x}; }   // i*v
__device__ __forceinline__ f2 cmul(f2 a, f2 b) {
    f2 t = a.x * b;
    return (f2){-a.y, a.y} * (f2){b.y, b.x} + t;   // (ar*br-ai*bi, ar*bi+ai*br)
}
__device__ __forceinline__ f2 csel(int s, f2 v0, f2 v1) { return s ? v1 : v0; }

template<int M>
__device__ __forceinline__ float shx(float v) {
    if constexpr (M < 32) {   // xor swizzle stays within 32-lane halves
        return __int_as_float(__builtin_amdgcn_ds_swizzle(
                   __float_as_int(v), (M << 10) | 0x1F));
    } else {
        return __shfl_xor(v, M, 64);
    }
}

// ---------------- setup: shared-weight trig -> d_ws (72 floats) --------------
// params[q*5+{0..4}]      = {w0, cos(b/2), sin(b/2), cos(g/2), sin(g/2)}  (layer1)
// params[40+q*4+{0..3}]   = {G00r, G00i, G01r, G01i}                      (layer2)
__global__ void qnn_setup(const float* __restrict__ w, float* __restrict__ p) {
    int t = threadIdx.x;
    if (t < 8) {
        int q = t;
        const float* wq = w + q * 3;
        p[q*5+0] = wq[0];
        p[q*5+1] = cosf(wq[1] * 0.5f);
        p[q*5+2] = sinf(wq[1] * 0.5f);
        p[q*5+3] = cosf(wq[2] * 0.5f);
        p[q*5+4] = sinf(wq[2] * 0.5f);
    } else if (t < 16) {
        int q = t - 8;
        const float* wq = w + (8 + q) * 3;
        float ca = cosf(wq[0]*0.5f), sa = sinf(wq[0]*0.5f);
        float cb = cosf(wq[1]*0.5f), sb = sinf(wq[1]*0.5f);
        float cg = cosf(wq[2]*0.5f), sg = sinf(wq[2]*0.5f);
        float A = cb*ca, Bv = sb*sa, C = sb*ca, D = cb*sa;
        float* gp = p + 40 + q*4;
        gp[0] = cg*A + sg*Bv;       // G00r
        gp[1] = cg*Bv - sg*A;       // G00i
        gp[2] = -(cg*C + sg*D);     // G01r
        gp[3] = sg*C - cg*D;        // G01i
    }
}

// cross-lane gate on wire Q (0..5): partner = lane ^ (32>>Q)
template<int Q>
__device__ __forceinline__ void gate_cross(f2 (&Aq)[4], float g00r, float g00i,
                                           float g01r, float g01i, int L) {
    const int tbit = (L >> (5 - Q)) & 1;
    const float di  = tbit ? -g00i : g00i;     // t=1: d=conj(G00), o=-conj(G01)
    const float orr = tbit ? -g01r : g01r;
    constexpr int M = 32 >> Q;
#pragma unroll
    for (int r = 0; r < 4; ++r) {
        f2 a  = Aq[r];
        f2 pp = (f2){ shx<M>(a.x), shx<M>(a.y) };
        Aq[r] = g00r*a + di*iswap(a) + orr*pp + g01i*iswap(pp);
    }
}

// in-register gate: X = amp(bit=0), Y = amp(bit=1)
__device__ __forceinline__ void gate_pair(f2& X, f2& Y, float g00r, float g00i,
                                          float g01r, float g01i) {
    f2 ix = iswap(X), iy = iswap(Y);
    f2 nx = g00r*X + g00i*ix + g01r*Y + g01i*iy;
    f2 ny = g00r*Y - g00i*iy - g01r*X + g01i*ix;
    X = nx; Y = ny;
}

template<int M>
__device__ __forceinline__ void wht_stage(float& v, int L) {
    float t = shx<M>(v);
    float u = v + t, d = t - v;
    v = (L & M) ? d : u;
}
template<int M>
__device__ __forceinline__ void sum_stage(float& v) { v += shx<M>(v); }

__global__ __launch_bounds__(256) void qnn_main(
        const float* __restrict__ x, const float* __restrict__ p,
        float* __restrict__ out, int B)
{
    const int lane = threadIdx.x & 63;
    const int b = blockIdx.x * 4 + (threadIdx.x >> 6);
    if (b >= B) return;                        // wave-uniform
    const int L = lane;
    const int L5=(L>>5)&1, L4=(L>>4)&1, L3=(L>>3)&1,
              L2=(L>>2)&1, L1=(L>>1)&1, L0=L&1;

    float xv = 0.f;
    if (lane < 8) xv = x[(size_t)b*8 + lane];

    // ---- per-qubit 2-vectors (embedding + layer-1 fused) ----
    f2 V0[8], V1[8];
#pragma unroll
    for (int q = 0; q < 8; ++q) {
        float ang = __shfl(xv, q, 64) + p[q*5+0];
        float sa, ca;
        __sincosf(ang * 0.5f, &sa, &ca);
        const float cb = p[q*5+1], sb = p[q*5+2], cg = p[q*5+3], sg = p[q*5+4];
        float A_ = cb*ca, Bv = sb*sa, C_ = sb*ca, D_ = cb*sa;
        V0[q] = (f2){cg*A_ + sg*Bv, cg*Bv - sg*A_};   // e^{-ig/2}(A+iB)
        V1[q] = (f2){cg*C_ + sg*D_, sg*C_ - cg*D_};   // e^{+ig/2}(C-iD)
    }

    // ---- product expansion with ring-1 folded in ----
    const int s0=L5, s1=L5^L4, s2=L4^L3, s3=L3^L2, s4=L2^L1, s5=L1^L0, s6=L0;

    f2 P = csel(s2, V0[2], V1[2]);
    P = cmul(P, csel(s3, V0[3], V1[3]));
    P = cmul(P, csel(s4, V0[4], V1[4]));
    P = cmul(P, csel(s5, V0[5], V1[5]));

    f2 a0 = csel(s0, V0[0], V1[0]), a1 = csel(s0, V1[0], V0[0]);
    f2 b0 = csel(s1, V0[1], V1[1]), b1 = csel(s1, V1[1], V0[1]);
    f2 M0 = cmul(P, cmul(a0, b0));
    f2 M1 = cmul(P, cmul(a1, b1));

    f2 w0 = csel(s6, V0[6], V1[6]), w1 = csel(s6, V1[6], V0[6]);
    f2 u0 = cmul(w0, V0[7]);
    f2 u1 = cmul(w0, V1[7]);
    f2 u2 = cmul(w1, V1[7]);
    f2 u3 = cmul(w1, V0[7]);

    f2 Aq[4];
    Aq[0] = cmul(M0, u0);
    Aq[1] = cmul(M1, u1);
    Aq[2] = cmul(M0, u2);
    Aq[3] = cmul(M1, u3);

    // ---- layer-2 fused gates ----
    gate_cross<0>(Aq, p[40+ 0], p[40+ 1], p[40+ 2], p[40+ 3], L);
    gate_cross<1>(Aq, p[40+ 4], p[40+ 5], p[40+ 6], p[40+ 7], L);
    gate_cross<2>(Aq, p[40+ 8], p[40+ 9], p[40+10], p[40+11], L);
    gate_cross<3>(Aq, p[40+12], p[40+13], p[40+14], p[40+15], L);
    gate_cross<4>(Aq, p[40+16], p[40+17], p[40+18], p[40+19], L);
    gate_cross<5>(Aq, p[40+20], p[40+21], p[40+22], p[40+23], L);
    // wire 6 (bit1 of r): pairs (0,2),(1,3)
    gate_pair(Aq[0], Aq[2], p[40+24], p[40+25], p[40+26], p[40+27]);
    gate_pair(Aq[1], Aq[3], p[40+24], p[40+25], p[40+26], p[40+27]);
    // wire 7 (bit0 of r): pairs (0,1),(2,3)
    gate_pair(Aq[0], Aq[1], p[40+28], p[40+29], p[40+30], p[40+31]);
    gate_pair(Aq[2], Aq[3], p[40+28], p[40+29], p[40+30], p[40+31]);

    // ---- probs + in-lane 4-WHT (lo masks 0,2,3) ----
    f2 q0 = Aq[0]*Aq[0], q1 = Aq[1]*Aq[1], q2 = Aq[2]*Aq[2], q3 = Aq[3]*Aq[3];
    float p0 = q0.x + q0.y, p1 = q1.x + q1.y, p2 = q2.x + q2.y, p3 = q3.x + q3.y;
    float s01 = p0 + p1, s23 = p2 + p3, d01 = p0 - p1, d23 = p2 - p3;
    float S0 = s01 + s23;    // lo mask 0
    float S2 = s01 - s23;    // lo mask 2
    float S3 = d01 - d23;    // lo mask 3

    // ---- cross-lane 64-WHT coefficients ----
    // wires 1..5: WHT64(S0) at lanes {48,56,60,62,63}
    float v = S0;
    wht_stage<1>(v, L); wht_stage<2>(v, L); wht_stage<4>(v, L);
    wht_stage<8>(v, L); wht_stage<16>(v, L); wht_stage<32>(v, L);
    // wire 6: full-parity signed sum of S2
    const int par6 = __popc(L) & 1;
    float w2s = par6 ? -S2 : S2;
    sum_stage<1>(w2s); sum_stage<2>(w2s); sum_stage<4>(w2s);
    sum_stage<8>(w2s); sum_stage<16>(w2s); sum_stage<32>(w2s);
    // wires 0,7: mask-31 signed S3; 5-stage sum within halves, then split
    const int par5 = __popc(L & 31) & 1;
    float w3s = par5 ? -S3 : S3;
    sum_stage<1>(w3s); sum_stage<2>(w3s); sum_stage<4>(w3s);
    sum_stage<8>(w3s); sum_stage<16>(w3s);
    float t32 = shx<32>(w3s);
    float out0v = w3s + t32;            // sum both halves
    float out7v = w3s - t32;            // (lower) - (upper), valid in lower half

    // ---- stores: each result written by the lane that holds it ----
    const size_t b8 = (size_t)b * 8;
    float vA = out0v;
    vA = (L == 7) ? out7v : vA;
    vA = (L == 6) ? w2s   : vA;
    if (L == 0 || L == 6 || L == 7) out[b8 + L] = vA;
    int oi = (L==48) ? 1 : (L==56) ? 2 : (L==60) ? 3 : (L==62) ? 4 : (L==63) ? 5 : -1;
    if (oi >= 0) out[b8 + oi] = v;
}

extern "C" void kernel_launch(void* const* d_in, const int* in_sizes, int n_in,
                              void* d_out, int out_size, void* d_ws, size_t ws_size,
                              hipStream_t stream) {
    const float* x = (const float*)d_in[0];
    const float* w = (const float*)d_in[1];
    float* out     = (float*)d_out;
    float* params  = (float*)d_ws;          // 72 floats
    int B = in_sizes[0] / 8;

    qnn_setup<<<1, 64, 0, stream>>>(w, params);
    int blocks = (B + 3) / 4;               // 4 waves/block, 1 sample/wave
    qnn_main<<<blocks, 256, 0, stream>>>(x, params, out, B);
}

// Round 3
// 163.155 us; speedup vs baseline: 1.2142x; 1.0422x over previous
//
#include <hip/hip_runtime.h>
#include <math.h>

// QNN: 8 qubits, DIM=256, 2 entangling layers, B samples.
//  - RX(x_q) fuses with layer-1 RX -> product state v_q = RZ RY RX |0>.
//  - CNOT ring 1 folded into product expansion (GF(2) basis permutation).
//  - CNOT ring 2 folded into measurement sign masks.
//  - Layer-2 = 8 fused SU(2) gates (shared weights, precomputed in d_ws).
//  - <Z_w> = 8 coeffs of WHT_256(probs) = (in-lane 4-WHT) x (cross-lane 64-WHT).
// Mapping: 1 wave = 1 sample; lane L holds amps j=4L+r (r=0..3) as f2 (re,im).
// R3: hand-packed VOP3P complex math (v_pk_fma_f32 + op_sel/neg folding):
//     complex mul / complex fma = 2 instructions each.

typedef float f2 __attribute__((ext_vector_type(2)));

// d = a*b (complex):  lo = ax*bx - ay*by, hi = ax*by + ay*bx   (2 VOP3P ops)
__device__ __forceinline__ f2 cmul_pk(f2 a, f2 b) {
    f2 t, d;
    asm("v_pk_mul_f32 %0, %1, %2 op_sel:[0,0] op_sel_hi:[0,1]"
        : "=v"(t) : "v"(a), "v"(b));                       // (ax*bx, ax*by)
    asm("v_pk_fma_f32 %0, %1, %2, %3 op_sel:[1,1,0] op_sel_hi:[1,0,1] neg_lo:[1,0,0] neg_hi:[0,0,0]"
        : "=v"(d) : "v"(a), "v"(b), "v"(t));               // (-ay*by+t.x, ay*bx+t.y)
    return d;
}
// d = acc + a*b (complex), 2 VOP3P ops
__device__ __forceinline__ f2 cmac_pk(f2 acc, f2 a, f2 b) {
    f2 t, d;
    asm("v_pk_fma_f32 %0, %1, %2, %3 op_sel:[0,0,0] op_sel_hi:[0,1,1]"
        : "=v"(t) : "v"(a), "v"(b), "v"(acc));             // (ax*bx+acc.x, ax*by+acc.y)
    asm("v_pk_fma_f32 %0, %1, %2, %3 op_sel:[1,1,0] op_sel_hi:[1,0,1] neg_lo:[1,0,0] neg_hi:[0,0,0]"
        : "=v"(d) : "v"(a), "v"(b), "v"(t));
    return d;
}
// (sb*ca, -cb*sa) from a=(cb,sb), b=(ca,sa): op_sel-swap src0 + neg_hi
__device__ __forceinline__ f2 pk_mul_swap_neghi(f2 a, f2 b) {
    f2 d;
    asm("v_pk_mul_f32 %0, %1, %2 op_sel:[1,0] op_sel_hi:[0,1] neg_hi:[1,0]"
        : "=v"(d) : "v"(a), "v"(b));
    return d;
}
__device__ __forceinline__ f2 csel(int s, f2 v0, f2 v1) { return s ? v1 : v0; }

template<int M>
__device__ __forceinline__ float shx(float v) {
    if constexpr (M < 32) {   // xor swizzle within 32-lane halves
        return __int_as_float(__builtin_amdgcn_ds_swizzle(
                   __float_as_int(v), (M << 10) | 0x1F));
    } else {
        return __shfl_xor(v, M, 64);
    }
}

// -------- setup: shared-weight trig -> d_ws (120 floats) --------
// p[0..7]       w0[q]
// p[8+2q]       (cb, sb)            f2 idx 4+q
// p[24+2q]      (cg, -sg)  = e0     f2 idx 12+q
// p[40+2q]      (cg,  sg)  = e1     f2 idx 20+q
// p[56+4q]      D=(g00r,g00i), O=(g01r,g01i)        f2 idx 28+2q, 29+2q
// p[88+4q]      Dc=(g00r,-g00i), Onc=(-g01r,g01i)   f2 idx 44+2q, 45+2q
__global__ void qnn_setup(const float* __restrict__ w, float* __restrict__ p) {
    int t = threadIdx.x;
    if (t < 8) {
        int q = t;
        const float* wq = w + q * 3;
        p[q] = wq[0];
        float cb = cosf(wq[1]*0.5f), sb = sinf(wq[1]*0.5f);
        float cg = cosf(wq[2]*0.5f), sg = sinf(wq[2]*0.5f);
        p[ 8+2*q] = cb;  p[ 9+2*q] = sb;
        p[24+2*q] = cg;  p[25+2*q] = -sg;
        p[40+2*q] = cg;  p[41+2*q] = sg;
    } else if (t < 16) {
        int q = t - 8;
        const float* wq = w + (8 + q) * 3;
        float ca = cosf(wq[0]*0.5f), sa = sinf(wq[0]*0.5f);
        float cb = cosf(wq[1]*0.5f), sb = sinf(wq[1]*0.5f);
        float cg = cosf(wq[2]*0.5f), sg = sinf(wq[2]*0.5f);
        float A = cb*ca, Bv = sb*sa, C = sb*ca, D = cb*sa;
        float g00r = cg*A + sg*Bv;
        float g00i = cg*Bv - sg*A;
        float g01r = -(cg*C + sg*D);
        float g01i = sg*C - cg*D;
        p[56+4*q] = g00r;  p[57+4*q] = g00i;
        p[58+4*q] = g01r;  p[59+4*q] = g01i;
        p[88+4*q] = g00r;  p[89+4*q] = -g00i;
        p[90+4*q] = -g01r; p[91+4*q] = g01i;
    }
}

// cross-lane gate on wire Q (0..5): partner = lane ^ (32>>Q)
// t=0: new = D*a + O*p ; t=1: new = conj(D)*a + (-conj(O))*p
template<int Q>
__device__ __forceinline__ void gate_cross(f2 (&Aq)[4], f2 D, f2 O, f2 Dc, f2 Onc,
                                           int L) {
    const int tbit = (L >> (5 - Q)) & 1;
    f2 d2 = csel(tbit, D, Dc);
    f2 o2 = csel(tbit, O, Onc);
    constexpr int M = 32 >> Q;
#pragma unroll
    for (int r = 0; r < 4; ++r) {
        f2 a = Aq[r];
        f2 pp; pp.x = shx<M>(a.x); pp.y = shx<M>(a.y);
        Aq[r] = cmac_pk(cmul_pk(d2, a), o2, pp);
    }
}

// in-register gate: X'= D*X + O*Y ; Y'= (-conj(O))*X + conj(D)*Y
__device__ __forceinline__ void gate_pair(f2& X, f2& Y, f2 D, f2 O, f2 Dc, f2 Onc) {
    f2 nx = cmac_pk(cmul_pk(D,   X), O,  Y);
    f2 ny = cmac_pk(cmul_pk(Onc, X), Dc, Y);
    X = nx; Y = ny;
}

template<int M>
__device__ __forceinline__ void wht_stage(float& v, int L) {
    float t = shx<M>(v);
    float u = v + t, d = t - v;
    v = (L & M) ? d : u;
}
template<int M>
__device__ __forceinline__ void sum_stage(float& v) { v += shx<M>(v); }

__global__ __launch_bounds__(256) void qnn_main(
        const float* __restrict__ x, const float* __restrict__ pf,
        float* __restrict__ out, int B)
{
    const f2* __restrict__ p2 = (const f2*)pf;
    const int lane = threadIdx.x & 63;
    const int b = blockIdx.x * 4 + (threadIdx.x >> 6);
    if (b >= B) return;                        // wave-uniform
    const int L = lane;
    const int L5=(L>>5)&1, L4=(L>>4)&1, L3=(L>>3)&1,
              L2=(L>>2)&1, L1=(L>>1)&1, L0=L&1;

    float xv = 0.f;
    if (lane < 8) xv = x[(size_t)b*8 + lane];

    // ---- per-qubit 2-vectors (embedding + layer-1 fused) ----
    // V0 = (cg - i sg)(A + iB),  V1 = (cg + i sg)(C - iD)
    // (A,B) = (cb*ca, sb*sa),  (C,-D) = (sb*ca, -cb*sa)
    f2 V0[8], V1[8];
#pragma unroll
    for (int q = 0; q < 8; ++q) {
        float ang = __shfl(xv, q, 64) + pf[q];
        float rev = ang * 0.07957747154594767f;        // (ang/2) / (2*pi)
        f2 casa;
        casa.x = __builtin_amdgcn_cosf(rev);           // cos(ang/2)
        casa.y = __builtin_amdgcn_sinf(rev);           // sin(ang/2)
        f2 cbsb = p2[4+q];
        f2 AB = cbsb * casa;                           // (cb*ca, sb*sa)
        f2 CD = pk_mul_swap_neghi(cbsb, casa);         // (sb*ca, -cb*sa)
        V0[q] = cmul_pk(p2[12+q], AB);
        V1[q] = cmul_pk(p2[20+q], CD);
    }

    // ---- product expansion with ring-1 folded in ----
    const int s0=L5, s1=L5^L4, s2=L4^L3, s3=L3^L2, s4=L2^L1, s5=L1^L0, s6=L0;

    f2 P = csel(s2, V0[2], V1[2]);
    P = cmul_pk(P, csel(s3, V0[3], V1[3]));
    P = cmul_pk(P, csel(s4, V0[4], V1[4]));
    P = cmul_pk(P, csel(s5, V0[5], V1[5]));

    f2 a0 = csel(s0, V0[0], V1[0]), a1 = csel(s0, V1[0], V0[0]);
    f2 b0 = csel(s1, V0[1], V1[1]), b1 = csel(s1, V1[1], V0[1]);
    f2 M0 = cmul_pk(P, cmul_pk(a0, b0));
    f2 M1 = cmul_pk(P, cmul_pk(a1, b1));

    f2 w0v = csel(s6, V0[6], V1[6]), w1v = csel(s6, V1[6], V0[6]);
    f2 u0 = cmul_pk(w0v, V0[7]);
    f2 u1 = cmul_pk(w0v, V1[7]);
    f2 u2 = cmul_pk(w1v, V1[7]);
    f2 u3 = cmul_pk(w1v, V0[7]);

    f2 Aq[4];
    Aq[0] = cmul_pk(M0, u0);
    Aq[1] = cmul_pk(M1, u1);
    Aq[2] = cmul_pk(M0, u2);
    Aq[3] = cmul_pk(M1, u3);

    // ---- layer-2 fused gates ----
    gate_cross<0>(Aq, p2[28], p2[29], p2[44], p2[45], L);
    gate_cross<1>(Aq, p2[30], p2[31], p2[46], p2[47], L);
    gate_cross<2>(Aq, p2[32], p2[33], p2[48], p2[49], L);
    gate_cross<3>(Aq, p2[34], p2[35], p2[50], p2[51], L);
    gate_cross<4>(Aq, p2[36], p2[37], p2[52], p2[53], L);
    gate_cross<5>(Aq, p2[38], p2[39], p2[54], p2[55], L);
    // wire 6 (bit1 of r): pairs (0,2),(1,3)
    gate_pair(Aq[0], Aq[2], p2[40], p2[41], p2[56], p2[57]);
    gate_pair(Aq[1], Aq[3], p2[40], p2[41], p2[56], p2[57]);
    // wire 7 (bit0 of r): pairs (0,1),(2,3)
    gate_pair(Aq[0], Aq[1], p2[42], p2[43], p2[58], p2[59]);
    gate_pair(Aq[2], Aq[3], p2[42], p2[43], p2[58], p2[59]);

    // ---- probs + in-lane 4-WHT (lo masks 0,2,3) ----
    f2 q0 = Aq[0]*Aq[0], q1 = Aq[1]*Aq[1], q2 = Aq[2]*Aq[2], q3 = Aq[3]*Aq[3];
    float p0 = q0.x + q0.y, p1 = q1.x + q1.y, p2v = q2.x + q2.y, p3 = q3.x + q3.y;
    float s01 = p0 + p1, s23 = p2v + p3, d01 = p0 - p1, d23 = p2v - p3;
    float S0 = s01 + s23;    // lo mask 0
    float S2 = s01 - s23;    // lo mask 2
    float S3 = d01 - d23;    // lo mask 3

    // ---- cross-lane 64-WHT coefficients ----
    // wires 1..5: WHT64(S0) at lanes {48,56,60,62,63}
    float v = S0;
    wht_stage<1>(v, L); wht_stage<2>(v, L); wht_stage<4>(v, L);
    wht_stage<8>(v, L); wht_stage<16>(v, L); wht_stage<32>(v, L);
    // wire 6: full-parity signed sum of S2
    const int par6 = __popc(L) & 1;
    float w2s = par6 ? -S2 : S2;
    sum_stage<1>(w2s); sum_stage<2>(w2s); sum_stage<4>(w2s);
    sum_stage<8>(w2s); sum_stage<16>(w2s); sum_stage<32>(w2s);
    // wires 0,7: mask-31 signed S3; 5-stage sum within halves, then split
    const int par5 = __popc(L & 31) & 1;
    float w3s = par5 ? -S3 : S3;
    sum_stage<1>(w3s); sum_stage<2>(w3s); sum_stage<4>(w3s);
    sum_stage<8>(w3s); sum_stage<16>(w3s);
    float t32 = shx<32>(w3s);
    float out0v = w3s + t32;            // sum both halves
    float out7v = w3s - t32;            // (lower) - (upper), valid in lower half

    // ---- stores: each result written by the lane that holds it ----
    const size_t b8 = (size_t)b * 8;
    float vA = out0v;
    vA = (L == 7) ? out7v : vA;
    vA = (L == 6) ? w2s   : vA;
    if (L == 0 || L == 6 || L == 7) out[b8 + L] = vA;
    int oi = (L==48) ? 1 : (L==56) ? 2 : (L==60) ? 3 : (L==62) ? 4 : (L==63) ? 5 : -1;
    if (oi >= 0) out[b8 + oi] = v;
}

extern "C" void kernel_launch(void* const* d_in, const int* in_sizes, int n_in,
                              void* d_out, int out_size, void* d_ws, size_t ws_size,
                              hipStream_t stream) {
    const float* x = (const float*)d_in[0];
    const float* w = (const float*)d_in[1];
    float* out     = (float*)d_out;
    float* params  = (float*)d_ws;          // 120 floats
    int B = in_sizes[0] / 8;

    qnn_setup<<<1, 64, 0, stream>>>(w, params);
    int blocks = (B + 3) / 4;               // 4 waves/block, 1 sample/wave
    qnn_main<<<blocks, 256, 0, stream>>>(x, params, out, B);
}

// Round 4
// 102.822 us; speedup vs baseline: 1.9267x; 1.5868x over previous
//
#include <hip/hip_runtime.h>
#include <hip/hip_bf16.h>
#include <math.h>

// QNN: 8 qubits, DIM=256, 2 entangling layers, B samples.
//  - RX(x_q) fuses with layer-1 RX -> product state v_q (V0=amp0, V1=amp1).
//  - CNOT ring 1 folded into product expansion: amp[n] = prod_q v_q[beta_q(n)],
//    beta (verified R0-R3): b0=n7^n0 b1=n7^n6^n0 b2=n6^n5 b3=n5^n4 b4=n4^n3
//    b5=n3^n2 b6=n2^n1 b7=n1^n0.
//  - Layer-2 gates are sample-independent: phi = A*S*B^T with A=G0..G3 tensor,
//    B=G4..G7 tensor (16x16 complex) -> 4x mfma_f32_16x16x32_bf16 per sample.
//  - CNOT ring 2 + <Z_w> folded into signed reductions of probs (WHT coeffs).
// Mapping: 1 wave = 16 samples (V-phase amortized), per sample: lane L holds
// S column n=L&15, rows 4h..4h+3 (h=L>>4) -> feeds MFMA B-layout directly.

typedef float f2 __attribute__((ext_vector_type(2)));
typedef float f4 __attribute__((ext_vector_type(4)));
typedef short short8 __attribute__((ext_vector_type(8)));

// complex mul, 2 VOP3P ops (verified R3)
__device__ __forceinline__ f2 cmul_pk(f2 a, f2 b) {
    f2 t, d;
    asm("v_pk_mul_f32 %0, %1, %2 op_sel:[0,0] op_sel_hi:[0,1]"
        : "=v"(t) : "v"(a), "v"(b));                       // (ax*bx, ax*by)
    asm("v_pk_fma_f32 %0, %1, %2, %3 op_sel:[1,1,0] op_sel_hi:[1,0,1] neg_lo:[1,0,0] neg_hi:[0,0,0]"
        : "=v"(d) : "v"(a), "v"(b), "v"(t));               // (-ay*by+t.x, ay*bx+t.y)
    return d;
}

template<int M>
__device__ __forceinline__ float shx(float v) {
    if constexpr (M < 32) {
        return __int_as_float(__builtin_amdgcn_ds_swizzle(
                   __float_as_int(v), (M << 10) | 0x1F));
    } else {
        return __shfl_xor(v, M, 64);
    }
}
template<int M>
__device__ __forceinline__ void wht_stage(float& v, int L) {
    float t = shx<M>(v);
    float u = v + t, d = t - v;
    v = (L & M) ? d : u;
}
template<int M>
__device__ __forceinline__ void sum_stage(float& v) { v += shx<M>(v); }

// ---------------- setup ----------------
// d_ws float region: p[0..7]=w0[q]; p[8+q*8..]=K1,K2,K3,K4 (f2 each) per qubit
//   K1=e^{-ig/2}cb, K2=i e^{-ig/2}sb, K3=e^{+ig/2}sb, K4=-i e^{+ig/2}cb
//   => V0 = ca*K1 + sa*K2, V1 = ca*K3 + sa*K4   (ca=cos(ang/2), sa=sin(ang/2))
// byte 512: A1 frag table (512 bf16), 1536: A2, 2560: B1, 3584: B2
//   A1=[Ar|-Ai], A2=[Ai|Ar] (16x32, A-layout); B1=[Br^T;-Bi^T], B2=[Bi^T;Br^T]
//   frag pos(m,k) = ((k>>3)*16 + m)*8 + (k&7)
__global__ void qnn_setup(const float* __restrict__ w, float* __restrict__ p) {
    int t = threadIdx.x;
    if (t < 8) {
        int q = t;
        float cb = cosf(w[q*3+1]*0.5f), sb = sinf(w[q*3+1]*0.5f);
        float cg = cosf(w[q*3+2]*0.5f), sg = sinf(w[q*3+2]*0.5f);
        p[q] = w[q*3+0];
        float* K = p + 8 + q*8;
        K[0] = cg*cb;  K[1] = -sg*cb;      // K1
        K[2] = sg*sb;  K[3] = cg*sb;       // K2
        K[4] = cg*sb;  K[5] = sg*sb;       // K3
        K[6] = sg*cb;  K[7] = -cg*cb;      // K4
    }
    // layer-2 gates (all threads, redundant)
    float G[8][2][2][2];
    for (int q = 0; q < 8; ++q) {
        const float* wq = w + (8+q)*3;
        float ca = cosf(wq[0]*0.5f), sa = sinf(wq[0]*0.5f);
        float cb = cosf(wq[1]*0.5f), sb = sinf(wq[1]*0.5f);
        float cg = cosf(wq[2]*0.5f), sg = sinf(wq[2]*0.5f);
        float A = cb*ca, Bv = sb*sa, C = sb*ca, D = cb*sa;
        float g00r = cg*A + sg*Bv, g00i = cg*Bv - sg*A;
        float g01r = -(cg*C + sg*D), g01i = sg*C - cg*D;
        G[q][0][0][0]=g00r;  G[q][0][0][1]=g00i;
        G[q][0][1][0]=g01r;  G[q][0][1][1]=g01i;
        G[q][1][0][0]=-g01r; G[q][1][0][1]=g01i;    // -conj(G01)
        G[q][1][1][0]=g00r;  G[q][1][1][1]=-g00i;   // conj(G00)
    }
    int m = t & 15, k2 = t >> 4;
    // Aten[m][k2] (out=m over wires0-3, wire0=MSB), Bten[n=m][k2] (out=n wires4-7)
    float ar = 1.f, ai = 0.f, br = 1.f, bi = 0.f;
    for (int j = 0; j < 4; ++j) {
        int bm = (m >> (3-j)) & 1, bk = (k2 >> (3-j)) & 1;
        float gr = G[j][bm][bk][0],  gi = G[j][bm][bk][1];
        float nr = ar*gr - ai*gi, ni = ar*gi + ai*gr; ar = nr; ai = ni;
        float hr = G[4+j][bm][bk][0], hi = G[4+j][bm][bk][1];
        float mr = br*hr - bi*hi, mi = br*hi + bi*hr; br = mr; bi = mi;
    }
    __hip_bfloat16* A1 = (__hip_bfloat16*)((char*)p + 512);
    __hip_bfloat16* A2 = A1 + 512;
    __hip_bfloat16* B1 = A1 + 1024;
    __hip_bfloat16* B2 = A1 + 1536;
    int p0 = ((k2 >> 3)*16 + m)*8 + (k2 & 7);
    int k3 = k2 + 16;
    int p1 = ((k3 >> 3)*16 + m)*8 + (k3 & 7);
    A1[p0] = __float2bfloat16(ar);   A1[p1] = __float2bfloat16(-ai);
    A2[p0] = __float2bfloat16(ai);   A2[p1] = __float2bfloat16(ar);
    B1[p0] = __float2bfloat16(br);   B1[p1] = __float2bfloat16(-bi);
    B2[p0] = __float2bfloat16(bi);   B2[p1] = __float2bfloat16(br);
}

__global__ __launch_bounds__(256) void qnn_main(
        const float* __restrict__ x, const float* __restrict__ p,
        float* __restrict__ out, int B)
{
    __shared__ __align__(16) char smem[16384];
    const int lane = threadIdx.x & 63;
    const int wid  = threadIdx.x >> 6;
    const int L = lane;
    const int b0 = (blockIdx.x * 4 + wid) * 16;
    if (b0 >= B) return;

    char* wb = smem + wid * 4096;
    f4*   VT = (f4*)wb;                 // 16 samples x 8 qubits x (V0,V1) = 2KB
    char* G1 = wb + 2048;               // S staging: Sr(512B col-major) + Si(512B)
    char* G2 = wb + 3072;               // M staging: 16x16 dwords (Mr,Mi) bf16 pairs

    // constant frags (loop-invariant)
    const short8* fr = (const short8*)((const char*)p + 512);
    short8 A1f = fr[L], A2f = fr[64 + L], B1f = fr[128 + L], B2f = fr[192 + L];

    // ---- V phase: 16 samples x 8 qubits over 64 lanes (2 builds/lane) ----
    {
        int sI = L >> 2, qp = (L & 3) * 2;
        float2 xv  = ((const float2*)x)[(size_t)(b0 + sI)*4 + (L & 3)];
        float2 w0p = ((const float2*)p)[qp >> 1];
        const f4* Kt = (const f4*)(p + 8);
#pragma unroll
        for (int u = 0; u < 2; ++u) {
            int q = qp + u;
            float ang = (u ? xv.y : xv.x) + (u ? w0p.y : w0p.x);
            float rev = ang * 0.07957747154594767f;      // (ang/2)/(2pi)
            float ca = __builtin_amdgcn_cosf(rev);
            float sa = __builtin_amdgcn_sinf(rev);
            f4 Ka = Kt[q*2], Kb = Kt[q*2+1];
            f4 v;
            v.x = ca*Ka.x + sa*Ka.z;  v.y = ca*Ka.y + sa*Ka.w;   // V0
            v.z = ca*Kb.x + sa*Kb.z;  v.w = ca*Kb.y + sa*Kb.w;   // V1
            VT[sI*8 + q] = v;
        }
    }
    // same-wave LDS ordering is in-order; no barrier needed (regions per-wave)

    // ---- hoisted lane constants ----
    const int  hq  = L >> 4;            // 0..3
    const int  col = L & 15;
    const bool c0 = ((L>>5) ^ L) & 1;
    const bool c1 = ((L>>5) ^ (L>>4) ^ L) & 1;
    const bool c5 = ((L>>3) ^ (L>>2)) & 1;
    const bool c6 = ((L>>2) ^ (L>>1)) & 1;
    const bool c7 = ((L>>1) ^ L) & 1;
    const bool bL4 = (L>>4) & 1, bL3 = (L>>3) & 1;
    const float sgn48 = (__popc(L & 48) & 1) ? -1.f : 1.f;
    int oidx = -1;
    oidx = (L==31) ? 0 : oidx;  oidx = (L== 1) ? 1 : oidx;
    oidx = (L== 2) ? 2 : oidx;  oidx = (L==48) ? 3 : oidx;
    oidx = (L==56) ? 4 : oidx;  oidx = (L==60) ? 5 : oidx;
    oidx = (L==62) ? 6 : oidx;  oidx = (L==63) ? 7 : oidx;
    // glue addresses
    char* wSr = G1 + col*32 + hq*8;                      // amp rows 4h..4h+3
    char* wSi = wSr + 512;
    char* rS  = G1 + col*32 + (hq & 1)*16 + (hq >> 1)*512;
    char* wM  = G2 + hq*256 + col*4;                     // rows 4h.., stride 64B
    char* rM  = G2 + col*64 + (hq & 1)*32;               // row m=col, col half
    const unsigned selM = (hq >> 1) ? 0x07060302u : 0x05040100u;
    const f4 zz = {0.f, 0.f, 0.f, 0.f};

    for (int s = 0; s < 16; ++s) {
        // ---- read V (broadcast) ----
        f4 vv0 = VT[s*8+0], vv1 = VT[s*8+1], vv2 = VT[s*8+2], vv3 = VT[s*8+3];
        f4 vv4 = VT[s*8+4], vv5 = VT[s*8+5], vv6 = VT[s*8+6], vv7 = VT[s*8+7];
        // ---- product expansion (ring-1 folded) ----
        f2 f0 = c0 ? (f2){vv0.z,vv0.w} : (f2){vv0.x,vv0.y};
        f2 f1 = c1 ? (f2){vv1.z,vv1.w} : (f2){vv1.x,vv1.y};
        f2 f5 = c5 ? (f2){vv5.z,vv5.w} : (f2){vv5.x,vv5.y};
        f2 f6 = c6 ? (f2){vv6.z,vv6.w} : (f2){vv6.x,vv6.y};
        f2 f7 = c7 ? (f2){vv7.z,vv7.w} : (f2){vv7.x,vv7.y};
        f2 P5 = cmul_pk(cmul_pk(f0, f1), cmul_pk(f5, cmul_pk(f6, f7)));
        f2 V20 = {vv2.x,vv2.y}, V21 = {vv2.z,vv2.w};
        f2 V30 = {vv3.x,vv3.y}, V31 = {vv3.z,vv3.w};
        f2 V40 = {vv4.x,vv4.y}, V41 = {vv4.z,vv4.w};
        f2 C20 = bL4 ? V21 : V20, C21 = bL4 ? V20 : V21;
        f2 C40 = bL3 ? V41 : V40, C41 = bL3 ? V40 : V41;
        f2 Z00 = cmul_pk(V30, C40), Z01 = cmul_pk(V31, C41);
        f2 Z10 = cmul_pk(V31, C40), Z11 = cmul_pk(V30, C41);
        f2 X0 = cmul_pk(P5, C20),  X1 = cmul_pk(P5, C21);
        f2 a0 = cmul_pk(X0, Z00), a1 = cmul_pk(X0, Z01);
        f2 a2 = cmul_pk(X1, Z10), a3 = cmul_pk(X1, Z11);
        // ---- glue1: S -> LDS bf16 (Sr/Si col-major), read B-frag ----
        unsigned r0 = __float_as_uint(a0.x)+0x8000u, r1 = __float_as_uint(a1.x)+0x8000u;
        unsigned r2 = __float_as_uint(a2.x)+0x8000u, r3 = __float_as_uint(a3.x)+0x8000u;
        unsigned i0 = __float_as_uint(a0.y)+0x8000u, i1 = __float_as_uint(a1.y)+0x8000u;
        unsigned i2 = __float_as_uint(a2.y)+0x8000u, i3 = __float_as_uint(a3.y)+0x8000u;
        uint2 pr = { __builtin_amdgcn_perm(r1, r0, 0x07060302u),
                     __builtin_amdgcn_perm(r3, r2, 0x07060302u) };
        uint2 pi = { __builtin_amdgcn_perm(i1, i0, 0x07060302u),
                     __builtin_amdgcn_perm(i3, i2, 0x07060302u) };
        *(uint2*)wSr = pr;
        *(uint2*)wSi = pi;
        short8 sfrag = *(short8*)rS;
        // ---- stage-1 MFMA: M = A * S ----
        f4 mr = __builtin_amdgcn_mfma_f32_16x16x32_bf16(A1f, sfrag, zz, 0, 0, 0);
        f4 mi = __builtin_amdgcn_mfma_f32_16x16x32_bf16(A2f, sfrag, zz, 0, 0, 0);
        // ---- glue2: M -> LDS (row-major dword = (Mr,Mi) bf16 pair), read A-frag
        unsigned m0 = __builtin_amdgcn_perm(__float_as_uint(mi[0])+0x8000u,
                                            __float_as_uint(mr[0])+0x8000u, 0x07060302u);
        unsigned m1 = __builtin_amdgcn_perm(__float_as_uint(mi[1])+0x8000u,
                                            __float_as_uint(mr[1])+0x8000u, 0x07060302u);
        unsigned m2 = __builtin_amdgcn_perm(__float_as_uint(mi[2])+0x8000u,
                                            __float_as_uint(mr[2])+0x8000u, 0x07060302u);
        unsigned m3 = __builtin_amdgcn_perm(__float_as_uint(mi[3])+0x8000u,
                                            __float_as_uint(mr[3])+0x8000u, 0x07060302u);
        *(unsigned*)(wM +   0) = m0;  *(unsigned*)(wM +  64) = m1;
        *(unsigned*)(wM + 128) = m2;  *(unsigned*)(wM + 192) = m3;
        uint4 da = *(uint4*)rM;
        uint4 db = *(uint4*)(rM + 16);
        uint4 nf;
        nf.x = __builtin_amdgcn_perm(da.y, da.x, selM);
        nf.y = __builtin_amdgcn_perm(da.w, da.z, selM);
        nf.z = __builtin_amdgcn_perm(db.y, db.x, selM);
        nf.w = __builtin_amdgcn_perm(db.w, db.z, selM);
        short8 nfrag;
        __builtin_memcpy(&nfrag, &nf, 16);
        // ---- stage-2 MFMA: phi = M * B^T ----
        f4 pr4 = __builtin_amdgcn_mfma_f32_16x16x32_bf16(nfrag, B1f, zz, 0, 0, 0);
        f4 pi4 = __builtin_amdgcn_mfma_f32_16x16x32_bf16(nfrag, B2f, zz, 0, 0, 0);
        // ---- probs + in-lane 4-WHT over (n5,n4) = reg bits ----
        float Q0 = pr4[0]*pr4[0] + pi4[0]*pi4[0];
        float Q1 = pr4[1]*pr4[1] + pi4[1]*pi4[1];
        float Q2 = pr4[2]*pr4[2] + pi4[2]*pi4[2];
        float Q3 = pr4[3]*pr4[3] + pi4[3]*pi4[3];
        float s01 = Q0 + Q1, s23 = Q2 + Q3;
        float S00 = s01 + s23;                // (n5,n4) mask 00
        float S10 = s01 - s23;                // mask 10 (sign by n5)
        float S11 = (Q0 - Q1) - (Q2 - Q3);    // mask 11
        // ---- cross-lane reductions ----
        float vW = S11;   // WHT64 -> lanes {31,48,56,60,62,63} = w {0,3,4,5,6,7}
        wht_stage<1>(vW, L); wht_stage<2>(vW, L); wht_stage<4>(vW, L);
        wht_stage<8>(vW, L); wht_stage<16>(vW, L); wht_stage<32>(vW, L);
        float vA = sgn48 * S00;               // w1: mask 48 signed sum
        sum_stage<1>(vA); sum_stage<2>(vA); sum_stage<4>(vA);
        sum_stage<8>(vA); sum_stage<16>(vA); sum_stage<32>(vA);
        float vB = sgn48 * S10;               // w2: mask 48 signed sum
        sum_stage<1>(vB); sum_stage<2>(vB); sum_stage<4>(vB);
        sum_stage<8>(vB); sum_stage<16>(vB); sum_stage<32>(vB);
        // ---- store ----
        float oval = (L == 1) ? vA : ((L == 2) ? vB : vW);
        if (oidx >= 0) out[(size_t)(b0 + s)*8 + oidx] = oval;
    }
}

extern "C" void kernel_launch(void* const* d_in, const int* in_sizes, int n_in,
                              void* d_out, int out_size, void* d_ws, size_t ws_size,
                              hipStream_t stream) {
    const float* x = (const float*)d_in[0];
    const float* w = (const float*)d_in[1];
    float* outp    = (float*)d_out;
    float* params  = (float*)d_ws;        // 288B floats + frag tables (4.5KB)
    int B = in_sizes[0] / 8;

    qnn_setup<<<1, 256, 0, stream>>>(w, params);
    int blocks = (B + 63) / 64;           // 4 waves/block, 16 samples/wave
    qnn_main<<<blocks, 256, 0, stream>>>(x, params, outp, B);
}

// Round 5
// 101.325 us; speedup vs baseline: 1.9551x; 1.0148x over previous
//
#include <hip/hip_runtime.h>
#include <hip/hip_bf16.h>
#include <math.h>

// QNN: 8 qubits, DIM=256, 2 entangling layers, B samples.
//  - RX(x_q) fuses with layer-1 RX -> product state v_q (V0=amp0, V1=amp1).
//  - CNOT ring 1 folded into product expansion (GF(2) basis permutation).
//  - Layer-2 gates sample-independent: phi = A*S*B^T (A=G0..G3, B=G4..G7
//    16x16 complex) -> 4x mfma_f32_16x16x32_bf16 per sample.
//  - CNOT ring 2 + <Z_w> folded into signed reductions (WHT coeffs).
// Mapping: 1 wave = 16 samples; per sample lane L holds S column n=L&15,
// rows 4h..4h+3 (h=L>>4).
// R5: M-staging stride 64->80B (bank-conflict-free, b128-aligned) and
//     sample-loop unroll x2 with disjoint staging buffers (2 independent
//     chains/iteration -> latency hiding; DS in-order per wave was
//     serializing consecutive samples through the shared buffer).

typedef float f2 __attribute__((ext_vector_type(2)));
typedef float f4 __attribute__((ext_vector_type(4)));
typedef short short8 __attribute__((ext_vector_type(8)));

// complex mul, 2 VOP3P ops (verified R3/R4)
__device__ __forceinline__ f2 cmul_pk(f2 a, f2 b) {
    f2 t, d;
    asm("v_pk_mul_f32 %0, %1, %2 op_sel:[0,0] op_sel_hi:[0,1]"
        : "=v"(t) : "v"(a), "v"(b));                       // (ax*bx, ax*by)
    asm("v_pk_fma_f32 %0, %1, %2, %3 op_sel:[1,1,0] op_sel_hi:[1,0,1] neg_lo:[1,0,0] neg_hi:[0,0,0]"
        : "=v"(d) : "v"(a), "v"(b), "v"(t));               // (-ay*by+t.x, ay*bx+t.y)
    return d;
}

template<int M>
__device__ __forceinline__ float shx(float v) {
    if constexpr (M < 32) {
        return __int_as_float(__builtin_amdgcn_ds_swizzle(
                   __float_as_int(v), (M << 10) | 0x1F));
    } else {
        return __shfl_xor(v, M, 64);
    }
}
template<int M>
__device__ __forceinline__ void wht_stage(float& v, int L) {
    float t = shx<M>(v);
    float u = v + t, d = t - v;
    v = (L & M) ? d : u;
}
template<int M>
__device__ __forceinline__ void sum_stage(float& v) { v += shx<M>(v); }

// ---------------- setup (identical to R4) ----------------
__global__ void qnn_setup(const float* __restrict__ w, float* __restrict__ p) {
    int t = threadIdx.x;
    if (t < 8) {
        int q = t;
        float cb = cosf(w[q*3+1]*0.5f), sb = sinf(w[q*3+1]*0.5f);
        float cg = cosf(w[q*3+2]*0.5f), sg = sinf(w[q*3+2]*0.5f);
        p[q] = w[q*3+0];
        float* K = p + 8 + q*8;
        K[0] = cg*cb;  K[1] = -sg*cb;      // K1
        K[2] = sg*sb;  K[3] = cg*sb;       // K2
        K[4] = cg*sb;  K[5] = sg*sb;       // K3
        K[6] = sg*cb;  K[7] = -cg*cb;      // K4
    }
    float G[8][2][2][2];
    for (int q = 0; q < 8; ++q) {
        const float* wq = w + (8+q)*3;
        float ca = cosf(wq[0]*0.5f), sa = sinf(wq[0]*0.5f);
        float cb = cosf(wq[1]*0.5f), sb = sinf(wq[1]*0.5f);
        float cg = cosf(wq[2]*0.5f), sg = sinf(wq[2]*0.5f);
        float A = cb*ca, Bv = sb*sa, C = sb*ca, D = cb*sa;
        float g00r = cg*A + sg*Bv, g00i = cg*Bv - sg*A;
        float g01r = -(cg*C + sg*D), g01i = sg*C - cg*D;
        G[q][0][0][0]=g00r;  G[q][0][0][1]=g00i;
        G[q][0][1][0]=g01r;  G[q][0][1][1]=g01i;
        G[q][1][0][0]=-g01r; G[q][1][0][1]=g01i;
        G[q][1][1][0]=g00r;  G[q][1][1][1]=-g00i;
    }
    int m = t & 15, k2 = t >> 4;
    float ar = 1.f, ai = 0.f, br = 1.f, bi = 0.f;
    for (int j = 0; j < 4; ++j) {
        int bm = (m >> (3-j)) & 1, bk = (k2 >> (3-j)) & 1;
        float gr = G[j][bm][bk][0],  gi = G[j][bm][bk][1];
        float nr = ar*gr - ai*gi, ni = ar*gi + ai*gr; ar = nr; ai = ni;
        float hr = G[4+j][bm][bk][0], hi = G[4+j][bm][bk][1];
        float mr = br*hr - bi*hi, mi = br*hi + bi*hr; br = mr; bi = mi;
    }
    __hip_bfloat16* A1 = (__hip_bfloat16*)((char*)p + 512);
    __hip_bfloat16* A2 = A1 + 512;
    __hip_bfloat16* B1 = A1 + 1024;
    __hip_bfloat16* B2 = A1 + 1536;
    int p0 = ((k2 >> 3)*16 + m)*8 + (k2 & 7);
    int k3 = k2 + 16;
    int p1 = ((k3 >> 3)*16 + m)*8 + (k3 & 7);
    A1[p0] = __float2bfloat16(ar);   A1[p1] = __float2bfloat16(-ai);
    A2[p0] = __float2bfloat16(ai);   A2[p1] = __float2bfloat16(ar);
    B1[p0] = __float2bfloat16(br);   B1[p1] = __float2bfloat16(-bi);
    B2[p0] = __float2bfloat16(bi);   B2[p1] = __float2bfloat16(br);
}

#define WAVE_LDS 6656   // VT 2048 | S0 1024 | S1 1024 | M0 1280 | M1 1280

__global__ __launch_bounds__(256) void qnn_main(
        const float* __restrict__ x, const float* __restrict__ p,
        float* __restrict__ out, int B)
{
    __shared__ __align__(16) char smem[4 * WAVE_LDS];
    const int lane = threadIdx.x & 63;
    const int wid  = threadIdx.x >> 6;
    const int L = lane;
    const int b0 = (blockIdx.x * 4 + wid) * 16;
    if (b0 >= B) return;

    char* wb = smem + wid * WAVE_LDS;
    f4*   VT = (f4*)wb;                 // 16 samples x 8 qubits x (V0,V1) = 2KB
    char* S0b = wb + 2048;
    char* S1b = wb + 3072;
    char* M0b = wb + 4096;              // 16 rows x 80B (stride-20-dword, pad)
    char* M1b = wb + 5376;

    // constant frags (loop-invariant)
    const short8* fr = (const short8*)((const char*)p + 512);
    short8 A1f = fr[L], A2f = fr[64 + L], B1f = fr[128 + L], B2f = fr[192 + L];

    // ---- V phase: 16 samples x 8 qubits over 64 lanes (2 builds/lane) ----
    {
        int sI = L >> 2, qp = (L & 3) * 2;
        float2 xv  = ((const float2*)x)[(size_t)(b0 + sI)*4 + (L & 3)];
        float2 w0p = ((const float2*)p)[qp >> 1];
        const f4* Kt = (const f4*)(p + 8);
#pragma unroll
        for (int u = 0; u < 2; ++u) {
            int q = qp + u;
            float ang = (u ? xv.y : xv.x) + (u ? w0p.y : w0p.x);
            float rev = ang * 0.07957747154594767f;      // (ang/2)/(2pi)
            float ca = __builtin_amdgcn_cosf(rev);
            float sa = __builtin_amdgcn_sinf(rev);
            f4 Ka = Kt[q*2], Kb = Kt[q*2+1];
            f4 v;
            v.x = ca*Ka.x + sa*Ka.z;  v.y = ca*Ka.y + sa*Ka.w;   // V0
            v.z = ca*Kb.x + sa*Kb.z;  v.w = ca*Kb.y + sa*Kb.w;   // V1
            VT[sI*8 + q] = v;
        }
    }
    // same-wave LDS ordering is in-order; regions are per-wave -> no barrier

    // ---- hoisted lane constants ----
    const int  hq  = L >> 4;
    const int  col = L & 15;
    const bool c0 = ((L>>5) ^ L) & 1;
    const bool c1 = ((L>>5) ^ (L>>4) ^ L) & 1;
    const bool c5 = ((L>>3) ^ (L>>2)) & 1;
    const bool c6 = ((L>>2) ^ (L>>1)) & 1;
    const bool c7 = ((L>>1) ^ L) & 1;
    const bool bL4 = (L>>4) & 1, bL3 = (L>>3) & 1;
    const float sgn48 = (__popc(L & 48) & 1) ? -1.f : 1.f;
    int oidx = -1;
    oidx = (L==31) ? 0 : oidx;  oidx = (L== 1) ? 1 : oidx;
    oidx = (L== 2) ? 2 : oidx;  oidx = (L==48) ? 3 : oidx;
    oidx = (L==56) ? 4 : oidx;  oidx = (L==60) ? 5 : oidx;
    oidx = (L==62) ? 6 : oidx;  oidx = (L==63) ? 7 : oidx;

    // staging addresses, both buffers
    char* wSr0 = S0b + col*32 + hq*8;   char* wSi0 = wSr0 + 512;
    char* rS0  = S0b + col*32 + (hq & 1)*16 + (hq >> 1)*512;
    char* wSr1 = S1b + col*32 + hq*8;   char* wSi1 = wSr1 + 512;
    char* rS1  = S1b + col*32 + (hq & 1)*16 + (hq >> 1)*512;
    char* wM0  = M0b + hq*320 + col*4;                 // row 4hq+reg at +reg*80
    char* rM0  = M0b + col*80 + (hq & 1)*32;
    char* wM1  = M1b + hq*320 + col*4;
    char* rM1  = M1b + col*80 + (hq & 1)*32;
    const unsigned selM = (hq >> 1) ? 0x07060302u : 0x05040100u;
    const f4 zz = {0.f, 0.f, 0.f, 0.f};

    auto proc = [&](int s, char* wSr, char* wSi, char* rS, char* wM, char* rM) {
        // ---- read V (broadcast) ----
        f4 vv0 = VT[s*8+0], vv1 = VT[s*8+1], vv2 = VT[s*8+2], vv3 = VT[s*8+3];
        f4 vv4 = VT[s*8+4], vv5 = VT[s*8+5], vv6 = VT[s*8+6], vv7 = VT[s*8+7];
        // ---- product expansion (ring-1 folded) ----
        f2 f0 = c0 ? (f2){vv0.z,vv0.w} : (f2){vv0.x,vv0.y};
        f2 f1 = c1 ? (f2){vv1.z,vv1.w} : (f2){vv1.x,vv1.y};
        f2 f5 = c5 ? (f2){vv5.z,vv5.w} : (f2){vv5.x,vv5.y};
        f2 f6 = c6 ? (f2){vv6.z,vv6.w} : (f2){vv6.x,vv6.y};
        f2 f7 = c7 ? (f2){vv7.z,vv7.w} : (f2){vv7.x,vv7.y};
        f2 P5 = cmul_pk(cmul_pk(f0, f1), cmul_pk(f5, cmul_pk(f6, f7)));
        f2 V20 = {vv2.x,vv2.y}, V21 = {vv2.z,vv2.w};
        f2 V30 = {vv3.x,vv3.y}, V31 = {vv3.z,vv3.w};
        f2 V40 = {vv4.x,vv4.y}, V41 = {vv4.z,vv4.w};
        f2 C20 = bL4 ? V21 : V20, C21 = bL4 ? V20 : V21;
        f2 C40 = bL3 ? V41 : V40, C41 = bL3 ? V40 : V41;
        f2 Z00 = cmul_pk(V30, C40), Z01 = cmul_pk(V31, C41);
        f2 Z10 = cmul_pk(V31, C40), Z11 = cmul_pk(V30, C41);
        f2 X0 = cmul_pk(P5, C20),  X1 = cmul_pk(P5, C21);
        f2 a0 = cmul_pk(X0, Z00), a1 = cmul_pk(X0, Z01);
        f2 a2 = cmul_pk(X1, Z10), a3 = cmul_pk(X1, Z11);
        // ---- glue1: S -> LDS bf16 (Sr/Si col-major), read B-frag ----
        unsigned r0 = __float_as_uint(a0.x)+0x8000u, r1 = __float_as_uint(a1.x)+0x8000u;
        unsigned r2 = __float_as_uint(a2.x)+0x8000u, r3 = __float_as_uint(a3.x)+0x8000u;
        unsigned i0 = __float_as_uint(a0.y)+0x8000u, i1 = __float_as_uint(a1.y)+0x8000u;
        unsigned i2 = __float_as_uint(a2.y)+0x8000u, i3 = __float_as_uint(a3.y)+0x8000u;
        uint2 pr = { __builtin_amdgcn_perm(r1, r0, 0x07060302u),
                     __builtin_amdgcn_perm(r3, r2, 0x07060302u) };
        uint2 pi = { __builtin_amdgcn_perm(i1, i0, 0x07060302u),
                     __builtin_amdgcn_perm(i3, i2, 0x07060302u) };
        *(uint2*)wSr = pr;
        *(uint2*)wSi = pi;
        short8 sfrag = *(short8*)rS;
        // ---- stage-1 MFMA: M = A * S ----
        f4 mr = __builtin_amdgcn_mfma_f32_16x16x32_bf16(A1f, sfrag, zz, 0, 0, 0);
        f4 mi = __builtin_amdgcn_mfma_f32_16x16x32_bf16(A2f, sfrag, zz, 0, 0, 0);
        // ---- glue2: M -> LDS (row-major, stride 80B), read A-frag ----
        unsigned m0 = __builtin_amdgcn_perm(__float_as_uint(mi[0])+0x8000u,
                                            __float_as_uint(mr[0])+0x8000u, 0x07060302u);
        unsigned m1 = __builtin_amdgcn_perm(__float_as_uint(mi[1])+0x8000u,
                                            __float_as_uint(mr[1])+0x8000u, 0x07060302u);
        unsigned m2 = __builtin_amdgcn_perm(__float_as_uint(mi[2])+0x8000u,
                                            __float_as_uint(mr[2])+0x8000u, 0x07060302u);
        unsigned m3 = __builtin_amdgcn_perm(__float_as_uint(mi[3])+0x8000u,
                                            __float_as_uint(mr[3])+0x8000u, 0x07060302u);
        *(unsigned*)(wM +   0) = m0;  *(unsigned*)(wM +  80) = m1;
        *(unsigned*)(wM + 160) = m2;  *(unsigned*)(wM + 240) = m3;
        uint4 da = *(uint4*)rM;
        uint4 db = *(uint4*)(rM + 16);
        uint4 nf;
        nf.x = __builtin_amdgcn_perm(da.y, da.x, selM);
        nf.y = __builtin_amdgcn_perm(da.w, da.z, selM);
        nf.z = __builtin_amdgcn_perm(db.y, db.x, selM);
        nf.w = __builtin_amdgcn_perm(db.w, db.z, selM);
        short8 nfrag;
        __builtin_memcpy(&nfrag, &nf, 16);
        // ---- stage-2 MFMA: phi = M * B^T ----
        f4 pr4 = __builtin_amdgcn_mfma_f32_16x16x32_bf16(nfrag, B1f, zz, 0, 0, 0);
        f4 pi4 = __builtin_amdgcn_mfma_f32_16x16x32_bf16(nfrag, B2f, zz, 0, 0, 0);
        // ---- probs + in-lane 4-WHT ----
        float Q0 = pr4[0]*pr4[0] + pi4[0]*pi4[0];
        float Q1 = pr4[1]*pr4[1] + pi4[1]*pi4[1];
        float Q2 = pr4[2]*pr4[2] + pi4[2]*pi4[2];
        float Q3 = pr4[3]*pr4[3] + pi4[3]*pi4[3];
        float s01 = Q0 + Q1, s23 = Q2 + Q3;
        float S00 = s01 + s23;
        float S10 = s01 - s23;
        float S11 = (Q0 - Q1) - (Q2 - Q3);
        // ---- cross-lane reductions ----
        float vW = S11;   // WHT64 -> lanes {31,48,56,60,62,63} = w {0,3..7}
        wht_stage<1>(vW, L); wht_stage<2>(vW, L); wht_stage<4>(vW, L);
        wht_stage<8>(vW, L); wht_stage<16>(vW, L); wht_stage<32>(vW, L);
        float vA = sgn48 * S00;               // w1
        sum_stage<1>(vA); sum_stage<2>(vA); sum_stage<4>(vA);
        sum_stage<8>(vA); sum_stage<16>(vA); sum_stage<32>(vA);
        float vB = sgn48 * S10;               // w2
        sum_stage<1>(vB); sum_stage<2>(vB); sum_stage<4>(vB);
        sum_stage<8>(vB); sum_stage<16>(vB); sum_stage<32>(vB);
        float oval = (L == 1) ? vA : ((L == 2) ? vB : vW);
        if (oidx >= 0) out[(size_t)(b0 + s)*8 + oidx] = oval;
    };

    for (int s = 0; s < 16; s += 2) {
        proc(s,     wSr0, wSi0, rS0, wM0, rM0);
        proc(s + 1, wSr1, wSi1, rS1, wM1, rM1);
    }
}

extern "C" void kernel_launch(void* const* d_in, const int* in_sizes, int n_in,
                              void* d_out, int out_size, void* d_ws, size_t ws_size,
                              hipStream_t stream) {
    const float* x = (const float*)d_in[0];
    const float* w = (const float*)d_in[1];
    float* outp    = (float*)d_out;
    float* params  = (float*)d_ws;
    int B = in_sizes[0] / 8;

    qnn_setup<<<1, 256, 0, stream>>>(w, params);
    int blocks = (B + 63) / 64;           // 4 waves/block, 16 samples/wave
    qnn_main<<<blocks, 256, 0, stream>>>(x, params, outp, B);
}

// Round 6
// 96.841 us; speedup vs baseline: 2.0457x; 1.0463x over previous
//
#include <hip/hip_runtime.h>
#include <hip/hip_bf16.h>
#include <math.h>

// QNN: 8 qubits, DIM=256, 2 entangling layers, B samples.
//  - RX(x_q) fuses with layer-1 RX -> product state v_q (V0,V1).
//  - CNOT ring 1 folded into product expansion (GF(2) basis permutation).
//  - Layer-2 gates sample-independent: phi = A*S*B^T via 4x mfma 16x16x32 bf16.
//  - CNOT ring 2 + <Z_w> + cross-lane reduction folded into ONE constant
//    +/-1 sign matrix applied as mfma_f32_16x16x32_f16 chain (R6):
//      out[s][w] = sum_{c,L} Sgn[(L,c)][w] * R[s][c][L],
//    R classes per lane: c0=S00, c1=S10, c2=S11 (in-lane 4-WHT of probs).
// Mapping: 1 wave = 16 samples; per sample lane L holds S column n=L&15,
// rows 4h..4h+3 (h=L>>4). Per-iter tail = 2 cvt_pkrtz + 1 ds_write_b64;
// epilogue every 8 samples = 8 chained f16 MFMAs + coalesced stores.

typedef float f2 __attribute__((ext_vector_type(2)));
typedef float f4 __attribute__((ext_vector_type(4)));
typedef short short8 __attribute__((ext_vector_type(8)));
typedef _Float16 half8 __attribute__((ext_vector_type(8)));

// complex mul, 2 VOP3P ops (verified R3-R5)
__device__ __forceinline__ f2 cmul_pk(f2 a, f2 b) {
    f2 t, d;
    asm("v_pk_mul_f32 %0, %1, %2 op_sel:[0,0] op_sel_hi:[0,1]"
        : "=v"(t) : "v"(a), "v"(b));                       // (ax*bx, ax*by)
    asm("v_pk_fma_f32 %0, %1, %2, %3 op_sel:[1,1,0] op_sel_hi:[1,0,1] neg_lo:[1,0,0] neg_hi:[0,0,0]"
        : "=v"(d) : "v"(a), "v"(b), "v"(t));               // (-ay*by+t.x, ay*bx+t.y)
    return d;
}

// ---------------- setup ----------------
// d_ws layout (bytes):
//   0..511     : floats p[]: p[0..7]=w0[q]; p[8+q*8..]=K1..K4 (f2) per qubit
//   512..4607  : A1/A2/B1/B2 bf16 frag tables (1KB each)
//   4608..12799: sign table SG: 8 chunks x 64 lanes x half8 (+-1/0, f16)
__global__ void qnn_setup(const float* __restrict__ w, float* __restrict__ p) {
    int t = threadIdx.x;
    if (t < 8) {
        int q = t;
        float cb = cosf(w[q*3+1]*0.5f), sb = sinf(w[q*3+1]*0.5f);
        float cg = cosf(w[q*3+2]*0.5f), sg = sinf(w[q*3+2]*0.5f);
        p[q] = w[q*3+0];
        float* K = p + 8 + q*8;
        K[0] = cg*cb;  K[1] = -sg*cb;      // K1
        K[2] = sg*sb;  K[3] = cg*sb;       // K2
        K[4] = cg*sb;  K[5] = sg*sb;       // K3
        K[6] = sg*cb;  K[7] = -cg*cb;      // K4
    }
    float G[8][2][2][2];
    for (int q = 0; q < 8; ++q) {
        const float* wq = w + (8+q)*3;
        float ca = cosf(wq[0]*0.5f), sa = sinf(wq[0]*0.5f);
        float cb = cosf(wq[1]*0.5f), sb = sinf(wq[1]*0.5f);
        float cg = cosf(wq[2]*0.5f), sg = sinf(wq[2]*0.5f);
        float A = cb*ca, Bv = sb*sa, C = sb*ca, D = cb*sa;
        float g00r = cg*A + sg*Bv, g00i = cg*Bv - sg*A;
        float g01r = -(cg*C + sg*D), g01i = sg*C - cg*D;
        G[q][0][0][0]=g00r;  G[q][0][0][1]=g00i;
        G[q][0][1][0]=g01r;  G[q][0][1][1]=g01i;
        G[q][1][0][0]=-g01r; G[q][1][0][1]=g01i;
        G[q][1][1][0]=g00r;  G[q][1][1][1]=-g00i;
    }
    int m = t & 15, k2 = t >> 4;
    float ar = 1.f, ai = 0.f, br = 1.f, bi = 0.f;
    for (int j = 0; j < 4; ++j) {
        int bm = (m >> (3-j)) & 1, bk = (k2 >> (3-j)) & 1;
        float gr = G[j][bm][bk][0],  gi = G[j][bm][bk][1];
        float nr = ar*gr - ai*gi, ni = ar*gi + ai*gr; ar = nr; ai = ni;
        float hr = G[4+j][bm][bk][0], hi = G[4+j][bm][bk][1];
        float mr = br*hr - bi*hi, mi = br*hi + bi*hr; br = mr; bi = mi;
    }
    __hip_bfloat16* A1 = (__hip_bfloat16*)((char*)p + 512);
    __hip_bfloat16* A2 = A1 + 512;
    __hip_bfloat16* B1 = A1 + 1024;
    __hip_bfloat16* B2 = A1 + 1536;
    int p0 = ((k2 >> 3)*16 + m)*8 + (k2 & 7);
    int k3 = k2 + 16;
    int p1 = ((k3 >> 3)*16 + m)*8 + (k3 & 7);
    A1[p0] = __float2bfloat16(ar);   A1[p1] = __float2bfloat16(-ai);
    A2[p0] = __float2bfloat16(ai);   A2[p1] = __float2bfloat16(ar);
    B1[p0] = __float2bfloat16(br);   B1[p1] = __float2bfloat16(-bi);
    B2[p0] = __float2bfloat16(bi);   B2[p1] = __float2bfloat16(br);

    // sign table for the reduction GEMM.  k = Lp*4 + c (c=3 dummy), K=256.
    // w classes: {S11,S00,S10,S11,S11,S11,S11,S11}; lane masks per w below.
    const int cls[8] = {2, 0, 1, 2, 2, 2, 2, 2};
    const int msk[8] = {31, 48, 48, 48, 56, 60, 62, 63};
    _Float16* SG = (_Float16*)((char*)p + 4608);
    for (int e = t; e < 512; e += 256) {
        int tt = e >> 6, l = e & 63, n = l & 15, quad = l >> 4;
        for (int j = 0; j < 8; ++j) {
            int k  = tt*32 + quad*8 + j;
            int Lp = k >> 2, c = k & 3;
            float v = 0.f;
            if (n < 8 && c == cls[n])
                v = (__popc(msk[n] & Lp) & 1) ? -1.f : 1.f;
            SG[e*8 + j] = (_Float16)v;
        }
    }
}

// per-wave LDS: VT 2048 | S 1024 | M 1280 | R 4352  (8704 B)
#define WAVE_LDS 8704

__global__ __launch_bounds__(256) void qnn_main(
        const float* __restrict__ x, const float* __restrict__ p,
        float* __restrict__ out, int B)
{
    __shared__ __align__(16) char smem[4 * WAVE_LDS];
    const int lane = threadIdx.x & 63;
    const int wid  = threadIdx.x >> 6;
    const int L = lane;
    const int b0 = (blockIdx.x * 4 + wid) * 16;
    if (b0 >= B) return;

    char* wb = smem + wid * WAVE_LDS;
    f4*   VT = (f4*)wb;                 // 16 samples x 8 qubits x (V0,V1)
    char* Sb = wb + 2048;
    char* Mb = wb + 3072;               // 16 rows x 80B (padded, conflict-free)
    char* Rb = wb + 4352;               // 8 samples x 544B (padded) f16 classes

    // constant frags (loop-invariant)
    const short8* fr = (const short8*)((const char*)p + 512);
    short8 A1f = fr[L], A2f = fr[64 + L], B1f = fr[128 + L], B2f = fr[192 + L];
    const half8* sgt = (const half8*)((const char*)p + 4608);

    // ---- V phase: 16 samples x 8 qubits over 64 lanes (2 builds/lane) ----
    {
        int sI = L >> 2, qp = (L & 3) * 2;
        float2 xv  = ((const float2*)x)[(size_t)(b0 + sI)*4 + (L & 3)];
        float2 w0p = ((const float2*)p)[qp >> 1];
        const f4* Kt = (const f4*)(p + 8);
#pragma unroll
        for (int u = 0; u < 2; ++u) {
            int q = qp + u;
            float ang = (u ? xv.y : xv.x) + (u ? w0p.y : w0p.x);
            float rev = ang * 0.07957747154594767f;      // (ang/2)/(2pi)
            float ca = __builtin_amdgcn_cosf(rev);
            float sa = __builtin_amdgcn_sinf(rev);
            f4 Ka = Kt[q*2], Kb = Kt[q*2+1];
            f4 v;
            v.x = ca*Ka.x + sa*Ka.z;  v.y = ca*Ka.y + sa*Ka.w;   // V0
            v.z = ca*Kb.x + sa*Kb.z;  v.w = ca*Kb.y + sa*Kb.w;   // V1
            VT[sI*8 + q] = v;
        }
    }
    // same-wave LDS ordering is in-order; regions are per-wave -> no barrier

    // ---- hoisted lane constants ----
    const int  hq  = L >> 4;
    const int  col = L & 15;
    const bool c0 = ((L>>5) ^ L) & 1;
    const bool c1 = ((L>>5) ^ (L>>4) ^ L) & 1;
    const bool c5 = ((L>>3) ^ (L>>2)) & 1;
    const bool c6 = ((L>>2) ^ (L>>1)) & 1;
    const bool c7 = ((L>>1) ^ L) & 1;
    const bool bL4 = (L>>4) & 1, bL3 = (L>>3) & 1;

    char* wSr = Sb + col*32 + hq*8;     char* wSi = wSr + 512;
    char* rS  = Sb + col*32 + (hq & 1)*16 + (hq >> 1)*512;
    char* wM  = Mb + hq*320 + col*4;
    char* rM  = Mb + col*80 + (hq & 1)*32;
    char* Rw  = Rb + L*8;
    char* Rr  = Rb + (col & 7)*544 + hq*16;   // col>=8 clamped (rows discarded)
    const unsigned selM = (hq >> 1) ? 0x07060302u : 0x05040100u;
    const f4 zz = {0.f, 0.f, 0.f, 0.f};

    for (int h = 0; h < 2; ++h) {
        for (int s8 = 0; s8 < 8; ++s8) {
            const int s = h*8 + s8;
            // ---- read V (broadcast) ----
            f4 vv0 = VT[s*8+0], vv1 = VT[s*8+1], vv2 = VT[s*8+2], vv3 = VT[s*8+3];
            f4 vv4 = VT[s*8+4], vv5 = VT[s*8+5], vv6 = VT[s*8+6], vv7 = VT[s*8+7];
            // ---- product expansion (ring-1 folded) ----
            f2 f0 = c0 ? (f2){vv0.z,vv0.w} : (f2){vv0.x,vv0.y};
            f2 f1 = c1 ? (f2){vv1.z,vv1.w} : (f2){vv1.x,vv1.y};
            f2 f5 = c5 ? (f2){vv5.z,vv5.w} : (f2){vv5.x,vv5.y};
            f2 f6 = c6 ? (f2){vv6.z,vv6.w} : (f2){vv6.x,vv6.y};
            f2 f7 = c7 ? (f2){vv7.z,vv7.w} : (f2){vv7.x,vv7.y};
            f2 P5 = cmul_pk(cmul_pk(f0, f1), cmul_pk(f5, cmul_pk(f6, f7)));
            f2 V20 = {vv2.x,vv2.y}, V21 = {vv2.z,vv2.w};
            f2 V30 = {vv3.x,vv3.y}, V31 = {vv3.z,vv3.w};
            f2 V40 = {vv4.x,vv4.y}, V41 = {vv4.z,vv4.w};
            f2 C20 = bL4 ? V21 : V20, C21 = bL4 ? V20 : V21;
            f2 C40 = bL3 ? V41 : V40, C41 = bL3 ? V40 : V41;
            f2 Z00 = cmul_pk(V30, C40), Z01 = cmul_pk(V31, C41);
            f2 Z10 = cmul_pk(V31, C40), Z11 = cmul_pk(V30, C41);
            f2 X0 = cmul_pk(P5, C20),  X1 = cmul_pk(P5, C21);
            f2 a0 = cmul_pk(X0, Z00), a1 = cmul_pk(X0, Z01);
            f2 a2 = cmul_pk(X1, Z10), a3 = cmul_pk(X1, Z11);
            // ---- glue1: S -> LDS bf16, read B-frag ----
            unsigned r0 = __float_as_uint(a0.x)+0x8000u, r1 = __float_as_uint(a1.x)+0x8000u;
            unsigned r2 = __float_as_uint(a2.x)+0x8000u, r3 = __float_as_uint(a3.x)+0x8000u;
            unsigned i0 = __float_as_uint(a0.y)+0x8000u, i1 = __float_as_uint(a1.y)+0x8000u;
            unsigned i2 = __float_as_uint(a2.y)+0x8000u, i3 = __float_as_uint(a3.y)+0x8000u;
            uint2 pr = { __builtin_amdgcn_perm(r1, r0, 0x07060302u),
                         __builtin_amdgcn_perm(r3, r2, 0x07060302u) };
            uint2 pi = { __builtin_amdgcn_perm(i1, i0, 0x07060302u),
                         __builtin_amdgcn_perm(i3, i2, 0x07060302u) };
            *(uint2*)wSr = pr;
            *(uint2*)wSi = pi;
            short8 sfrag = *(short8*)rS;
            // ---- stage-1 MFMA: M = A * S ----
            f4 mr = __builtin_amdgcn_mfma_f32_16x16x32_bf16(A1f, sfrag, zz, 0, 0, 0);
            f4 mi = __builtin_amdgcn_mfma_f32_16x16x32_bf16(A2f, sfrag, zz, 0, 0, 0);
            // ---- glue2: M -> LDS (stride 80B), read A-frag ----
            unsigned m0 = __builtin_amdgcn_perm(__float_as_uint(mi[0])+0x8000u,
                                                __float_as_uint(mr[0])+0x8000u, 0x07060302u);
            unsigned m1 = __builtin_amdgcn_perm(__float_as_uint(mi[1])+0x8000u,
                                                __float_as_uint(mr[1])+0x8000u, 0x07060302u);
            unsigned m2 = __builtin_amdgcn_perm(__float_as_uint(mi[2])+0x8000u,
                                                __float_as_uint(mr[2])+0x8000u, 0x07060302u);
            unsigned m3 = __builtin_amdgcn_perm(__float_as_uint(mi[3])+0x8000u,
                                                __float_as_uint(mr[3])+0x8000u, 0x07060302u);
            *(unsigned*)(wM +   0) = m0;  *(unsigned*)(wM +  80) = m1;
            *(unsigned*)(wM + 160) = m2;  *(unsigned*)(wM + 240) = m3;
            uint4 da = *(uint4*)rM;
            uint4 db = *(uint4*)(rM + 16);
            uint4 nf;
            nf.x = __builtin_amdgcn_perm(da.y, da.x, selM);
            nf.y = __builtin_amdgcn_perm(da.w, da.z, selM);
            nf.z = __builtin_amdgcn_perm(db.y, db.x, selM);
            nf.w = __builtin_amdgcn_perm(db.w, db.z, selM);
            short8 nfrag;
            __builtin_memcpy(&nfrag, &nf, 16);
            // ---- stage-2 MFMA: phi = M * B^T ----
            f4 pr4 = __builtin_amdgcn_mfma_f32_16x16x32_bf16(nfrag, B1f, zz, 0, 0, 0);
            f4 pi4 = __builtin_amdgcn_mfma_f32_16x16x32_bf16(nfrag, B2f, zz, 0, 0, 0);
            // ---- probs + in-lane 4-WHT -> 3 class values, stage to R ----
            float Q0 = pr4[0]*pr4[0] + pi4[0]*pi4[0];
            float Q1 = pr4[1]*pr4[1] + pi4[1]*pi4[1];
            float Q2 = pr4[2]*pr4[2] + pi4[2]*pi4[2];
            float Q3 = pr4[3]*pr4[3] + pi4[3]*pi4[3];
            float s01 = Q0 + Q1, s23 = Q2 + Q3;
            float S00 = s01 + s23;
            float S10 = s01 - s23;
            float S11 = (Q0 - Q1) - (Q2 - Q3);
            auto h01 = __builtin_amdgcn_cvt_pkrtz(S00, S10);   // f16x2
            auto h23 = __builtin_amdgcn_cvt_pkrtz(S11, 0.f);
            uint2 wv;
            __builtin_memcpy(&wv.x, &h01, 4);
            __builtin_memcpy(&wv.y, &h23, 4);
            *(uint2*)(Rw + s8*544) = wv;
        }
        // ---- epilogue: out[s][w] = R x Sgn  (8 chained f16 MFMAs) ----
        f4 acc = zz;
#pragma unroll
        for (int tt = 0; tt < 8; ++tt) {
            uint4 rv = *(uint4*)(Rr + tt*64);
            half8 af;
            __builtin_memcpy(&af, &rv, 16);
            acc = __builtin_amdgcn_mfma_f32_16x16x32_f16(af, sgt[tt*64 + L], acc, 0, 0, 0);
        }
        if (hq < 2 && col < 8) {        // rows 0..7 = samples h*8..h*8+7
            size_t base = (size_t)(b0 + h*8 + hq*4) * 8 + col;
            out[base     ] = acc[0];
            out[base +  8] = acc[1];
            out[base + 16] = acc[2];
            out[base + 24] = acc[3];
        }
    }
}

extern "C" void kernel_launch(void* const* d_in, const int* in_sizes, int n_in,
                              void* d_out, int out_size, void* d_ws, size_t ws_size,
                              hipStream_t stream) {
    const float* x = (const float*)d_in[0];
    const float* w = (const float*)d_in[1];
    float* outp    = (float*)d_out;
    float* params  = (float*)d_ws;        // ~12.8 KB used
    int B = in_sizes[0] / 8;

    qnn_setup<<<1, 256, 0, stream>>>(w, params);
    int blocks = (B + 63) / 64;           // 4 waves/block, 16 samples/wave
    qnn_main<<<blocks, 256, 0, stream>>>(x, params, outp, B);
}